// Round 1
// 984.897 us; speedup vs baseline: 1.1869x; 1.1869x over previous
//
#include <hip/hip_runtime.h>

#define T_SZ 65536
#define K_SZ 2048
#define D_SZ 256

// numpy pairwise_sum replica for 128 contiguous squared elements.
// numpy: r[0..7] = a[0..7]; for i=8..120 step 8: r[j]+=a[i+j];
//        res = ((r0+r1)+(r2+r3))+((r4+r5)+(r6+r7))
// applied to a[i]^2 with each square rounded BEFORE the add (contract off).
__device__ __forceinline__ float pairwise128_sq(const float* __restrict__ a) {
#pragma clang fp contract(off)
  float r0 = a[0] * a[0], r1 = a[1] * a[1], r2 = a[2] * a[2], r3 = a[3] * a[3];
  float r4 = a[4] * a[4], r5 = a[5] * a[5], r6 = a[6] * a[6], r7 = a[7] * a[7];
#pragma unroll
  for (int i = 8; i < 128; i += 8) {
    r0 += a[i + 0] * a[i + 0];
    r1 += a[i + 1] * a[i + 1];
    r2 += a[i + 2] * a[i + 2];
    r3 += a[i + 3] * a[i + 3];
    r4 += a[i + 4] * a[i + 4];
    r5 += a[i + 5] * a[i + 5];
    r6 += a[i + 6] * a[i + 6];
    r7 += a[i + 7] * a[i + 7];
  }
  return ((r0 + r1) + (r2 + r3)) + ((r4 + r5) + (r6 + r7));
}

// e_sq[k] = numpy-pairwise sum of e[k][:]^2  (n=256 -> 128+128 split)
__global__ void esq_kernel(const float* __restrict__ e, float* __restrict__ esq) {
  int k = blockIdx.x * 64 + threadIdx.x;  // 32 blocks x 64 = 2048
  const float* er = e + (size_t)k * D_SZ;
  esq[k] = pairwise128_sq(er) + pairwise128_sq(er + 128);
}

// Main kernel: per block 128 rows x 1024 codes (half the codebook, 8 chunks of 128).
// K split across 2 blocks per row-tile for 4 blocks/CU occupancy (grid 1024).
//
// R5 change: x no longer read per-q via VMEM broadcast loads (those issued
// 32 global_load_dwordx4 per dstep per wave with only 4 distinct 64B lines
// each -> ~1 L1 tag-probe/cycle/CU, saturating the TA/L1 path and capping
// VALUBusy at ~57% independent of occupancy). Both operands now stream
// through LDS, double-buffered per dstep:
//   es[2][128][16]: col-group g = q ^ (k&3) ^ ((k>>2)&3)
//       read lanes vary tx (k=16c+tx) -> 2-way bank aliasing (free, m136)
//   xs[2][128][16]: col-group g = q ^ ((row>>3)&3)
//       read lanes vary ty (row=8ty+r, rows differ by 8) -> conflict-free
// j (element within float4) is never swizzled, so the d-order inside each
// quad -- and therefore every FMA accumulation chain -- is bit-identical to
// the verified version. LDS = 2*(8KB+8KB)+512B = 33,280 B -> 4 blocks/CU.
__global__ __launch_bounds__(256, 1) void vq_argmin_kernel(
    const float* __restrict__ x, const float* __restrict__ e,
    const float* __restrict__ esq_g, float* __restrict__ cand_v,
    int* __restrict__ cand_i) {
  __shared__ __align__(16) float es[2][128][16];
  __shared__ __align__(16) float xs[2][128][16];
  __shared__ float xsq_s[128];

  const int tid = threadIdx.x;
  const int tx = tid & 15;
  const int ty = tid >> 4;
  const int half = blockIdx.x & 1;
  const int rowbase = (blockIdx.x >> 1) * 128;
  const int kbase = half * 1024;

  // --- x_sq for the block's 128 rows, numpy pairwise (threads 0..127, once) ---
  if (tid < 128) {
    const float* xr = x + (size_t)(rowbase + tid) * D_SZ;
    xsq_s[tid] = pairwise128_sq(xr) + pairwise128_sq(xr + 128);
  }

  const float4* x4 = reinterpret_cast<const float4*>(x);
  const float4* e4 = reinterpret_cast<const float4*>(e);

  // e staging: thread covers codes k0 and 64+k0, quad q0.
  // h(k) = (k&3)^((k>>2)&3); h(64+k0)==h(k0), so one col serves both rows.
  const int k0 = tid >> 2;  // 0..63
  const int q0 = tid & 3;
  const int ecol = 4 * (q0 ^ ((k0 & 3) ^ ((k0 >> 2) & 3)));

  // x staging: thread covers rows xr0 and 64+xr0, quad xq.
  // g(row,q) = q ^ ((row>>3)&3); (64+xr0)>>3 == xr0>>3 (mod 4), same col.
  const int xr0 = tid >> 2;  // 0..63
  const int xq = tid & 3;
  const int xcol = 4 * (xq ^ ((tid >> 5) & 3));

  float4 pe0, pe1, px0, px1;  // global -> reg -> LDS staging registers

  auto prefetch = [&](int round) {
    const int chunk = round >> 4, dstep = round & 15;
    pe0 = e4[(size_t)(kbase + chunk * 128 + k0) * 64 + dstep * 4 + q0];
    pe1 = e4[(size_t)(kbase + chunk * 128 + 64 + k0) * 64 + dstep * 4 + q0];
    // x slice depends only on dstep (identical across chunks)
    px0 = x4[(size_t)(rowbase + xr0) * 64 + dstep * 4 + xq];
    px1 = x4[(size_t)(rowbase + 64 + xr0) * 64 + dstep * 4 + xq];
  };

  auto write_lds = [&](int buf) {
    *reinterpret_cast<float4*>(&es[buf][k0][ecol]) = pe0;
    *reinterpret_cast<float4*>(&es[buf][64 + k0][ecol]) = pe1;
    *reinterpret_cast<float4*>(&xs[buf][xr0][xcol]) = px0;
    *reinterpret_cast<float4*>(&xs[buf][64 + xr0][xcol]) = px1;
  };

  prefetch(0);
  write_lds(0);
  __syncthreads();

  float acc[8][8];
#pragma unroll
  for (int r = 0; r < 8; ++r)
#pragma unroll
    for (int c = 0; c < 8; ++c) acc[r][c] = 0.0f;

  float bestv[8];
  int besti[8];
#pragma unroll
  for (int r = 0; r < 8; ++r) {
    bestv[r] = 3.402823466e38f;
    besti[r] = 0;
  }

  // per-thread constant swizzle keys for the read side
  const int htx = (tx & 3) ^ ((tx >> 2) & 3);  // es: h(16c+tx) == h(tx)
  const int hty = ty & 3;                      // xs: (8ty+r)>>3 == ty

#pragma unroll 1
  for (int chunk = 0; chunk < 8; ++chunk) {
#pragma unroll 1
    for (int dstep = 0; dstep < 16; ++dstep) {
      const int round = chunk * 16 + dstep;
      const int buf = round & 1;
      if (round < 127) prefetch(round + 1);
#pragma unroll 1
      for (int q = 0; q < 4; ++q) {
        const int cx = 4 * (q ^ hty);
        const int ce = 4 * (q ^ htx);
        // this 4-d group of x (8 rows) from LDS, broadcast across tx lanes
        float4 xg[8];
#pragma unroll
        for (int r = 0; r < 8; ++r)
          xg[r] = *reinterpret_cast<const float4*>(&xs[buf][8 * ty + r][cx]);
#pragma unroll
        for (int c = 0; c < 8; ++c) {
          float4 ev = *reinterpret_cast<const float4*>(&es[buf][16 * c + tx][ce]);
#pragma unroll
          for (int r = 0; r < 8; ++r) {
            // d ascending within the quad -> global d order 0..255 sequential
            acc[r][c] = __builtin_fmaf(xg[r].x, ev.x, acc[r][c]);
            acc[r][c] = __builtin_fmaf(xg[r].y, ev.y, acc[r][c]);
            acc[r][c] = __builtin_fmaf(xg[r].z, ev.z, acc[r][c]);
            acc[r][c] = __builtin_fmaf(xg[r].w, ev.w, acc[r][c]);
          }
        }
      }
      if (round < 127) write_lds(buf ^ 1);
      __syncthreads();
    }
    // epilogue for this 128-code chunk: dist = (x_sq - 2*cross) + e_sq, running argmin
    const int nbase = kbase + chunk * 128;
#pragma unroll
    for (int c = 0; c < 8; ++c) {
      const int k = nbase + 16 * c + tx;  // ascending k within thread
      const float esq = esq_g[k];
#pragma unroll
      for (int r = 0; r < 8; ++r) {
        float xsq = xsq_s[8 * ty + r];          // broadcast LDS read (free)
        float t1 = xsq - 2.0f * acc[r][c];      // 2*acc exact; matches np
        float dist = t1 + esq;
        bool better = dist < bestv[r];  // strict <: first (lowest k) wins ties
        bestv[r] = better ? dist : bestv[r];
        besti[r] = better ? k : besti[r];
        acc[r][c] = 0.0f;
      }
    }
  }

  // fold the 16 tx-lanes per row (lane bits 0..3 = tx); tie-break: lowest index
#pragma unroll
  for (int m = 1; m < 16; m <<= 1) {
#pragma unroll
    for (int r = 0; r < 8; ++r) {
      float ov = __shfl_xor(bestv[r], m, 64);
      int oi = __shfl_xor(besti[r], m, 64);
      bool take = (ov < bestv[r]) || ((ov == bestv[r]) && (oi < besti[r]));
      bestv[r] = take ? ov : bestv[r];
      besti[r] = take ? oi : besti[r];
    }
  }
  if (tx == 0) {
#pragma unroll
    for (int r = 0; r < 8; ++r) {
      cand_v[half * T_SZ + rowbase + 8 * ty + r] = bestv[r];
      cand_i[half * T_SZ + rowbase + 8 * ty + r] = besti[r];
    }
  }
}

// Combine the two K-halves (strict < : half 0 wins ties -> lower index, matching
// np.argmin first-occurrence), then out0 = x + (e[idx] - x) elementwise fp32.
__global__ __launch_bounds__(256) void decode_kernel(
    const float* __restrict__ x, const float* __restrict__ e,
    const float* __restrict__ cand_v, const int* __restrict__ cand_i,
    float* __restrict__ out, float* __restrict__ outIdx) {
  size_t g = (size_t)blockIdx.x * 256 + threadIdx.x;  // float4 index
  size_t t = g >> 6;
  int q = (int)(g & 63);
  float v0 = cand_v[t], v1 = cand_v[T_SZ + t];
  int i0 = cand_i[t], i1 = cand_i[T_SZ + t];
  int idx = (v1 < v0) ? i1 : i0;  // wave-uniform (t uniform across the wave)
  if (q == 0) outIdx[t] = (float)idx;
  const float4* x4 = reinterpret_cast<const float4*>(x);
  const float4* e4 = reinterpret_cast<const float4*>(e);
  float4 xv = x4[t * 64 + q];
  float4 qv = e4[(size_t)idx * 64 + q];
  float4 o;
  o.x = xv.x + (qv.x - xv.x);
  o.y = xv.y + (qv.y - xv.y);
  o.z = xv.z + (qv.z - xv.z);
  o.w = xv.w + (qv.w - xv.w);
  reinterpret_cast<float4*>(out)[g] = o;
}

extern "C" void kernel_launch(void* const* d_in, const int* in_sizes, int n_in,
                              void* d_out, int out_size, void* d_ws, size_t ws_size,
                              hipStream_t stream) {
  const float* x = (const float*)d_in[0];      // (65536, 256) fp32
  const float* e = (const float*)d_in[1];      // (2048, 256) fp32
  float* out = (float*)d_out;                  // [T*D quantized | T indices-as-float]
  float* outIdx = out + (size_t)T_SZ * D_SZ;

  float* esq = (float*)d_ws;                       // 2048 floats
  float* cand_v = esq + K_SZ;                      // 2*T floats
  int* cand_i = (int*)(cand_v + 2 * T_SZ);         // 2*T ints

  esq_kernel<<<K_SZ / 64, 64, 0, stream>>>(e, esq);
  vq_argmin_kernel<<<(T_SZ / 128) * 2, 256, 0, stream>>>(x, e, esq, cand_v, cand_i);
  decode_kernel<<<(T_SZ * (D_SZ / 4)) / 256, 256, 0, stream>>>(x, e, cand_v, cand_i,
                                                               out, outIdx);
}

// Round 2
// 848.606 us; speedup vs baseline: 1.3775x; 1.1606x over previous
//
#include <hip/hip_runtime.h>

#define T_SZ 65536
#define K_SZ 2048
#define D_SZ 256

typedef unsigned short u16;
typedef short bf16x8 __attribute__((ext_vector_type(8)));
typedef float f32x4 __attribute__((ext_vector_type(4)));

// Sound certification threshold on distances. Worst-case |approx-exact| dist
// error (bf16x2 split, dropped h2g2 + residuals + fp32 accum rounding, with
// |e|<=1/2048 strictly and per-row sum|x| <= ~260) is ~2e-5. EPS_GAP=2e-4
// gives 10x margin; ~11% of rows get exact rescoring of banded candidates.
#define EPS_GAP 2.0e-4f
#define RINGCAP 5120

#define GLOAD_LDS16(g, l)                                                  \
  __builtin_amdgcn_global_load_lds(                                        \
      (const __attribute__((address_space(1))) unsigned int*)(g),          \
      (__attribute__((address_space(3))) unsigned int*)(l), 16, 0, 0)

__device__ __forceinline__ u16 f2bf(float f) {  // RNE float->bf16
  unsigned u = __float_as_uint(f);
  u += 0x7FFFu + ((u >> 16) & 1u);
  return (u16)(u >> 16);
}
__device__ __forceinline__ float bf2f(u16 h) { return __uint_as_float(((unsigned)h) << 16); }
// bank-swizzle key for 16B k-groups within a 64B row (keeps reads <=2-way).
// Correctness-safe by construction: conv bakes the same key into the global
// image that the fragment reads use (G21: both-sides-or-neither).
__device__ __forceinline__ int swz4(int row) { return (row & 3) ^ ((row >> 2) & 3); }

// numpy pairwise_sum replica for 128 contiguous squared elements (verified).
__device__ __forceinline__ float pairwise128_sq(const float* __restrict__ a) {
#pragma clang fp contract(off)
  float r0 = a[0] * a[0], r1 = a[1] * a[1], r2 = a[2] * a[2], r3 = a[3] * a[3];
  float r4 = a[4] * a[4], r5 = a[5] * a[5], r6 = a[6] * a[6], r7 = a[7] * a[7];
#pragma unroll
  for (int i = 8; i < 128; i += 8) {
    r0 += a[i + 0] * a[i + 0];
    r1 += a[i + 1] * a[i + 1];
    r2 += a[i + 2] * a[i + 2];
    r3 += a[i + 3] * a[i + 3];
    r4 += a[i + 4] * a[i + 4];
    r5 += a[i + 5] * a[i + 5];
    r6 += a[i + 6] * a[i + 6];
    r7 += a[i + 7] * a[i + 7];
  }
  return ((r0 + r1) + (r2 + r3)) + ((r4 + r5) + (r6 + r7));
}

__global__ void esq_kernel(const float* __restrict__ e, float* __restrict__ esq) {
  int k = blockIdx.x * 64 + threadIdx.x;
  const float* er = e + (size_t)k * D_SZ;
  esq[k] = pairwise128_sq(er) + pairwise128_sq(er + 128);
}

// Convert fp32 rows -> pre-tiled, pre-swizzled bf16 split image.
// dst layout per 128-row tile (131072 B): [step 0..15][row 0..127][G 0..3][j 0..7]
// steps 0-7: h1 = bf16(v), k = (step&7)*32 + 8*(G ^ swz4(row)) + j
// steps 8-15: h2 = bf16(v - fp32(h1)), same k mapping.
__global__ __launch_bounds__(256) void conv_kernel(const float* __restrict__ src,
                                                   u16* __restrict__ dst) {
  const int tile = blockIdx.x, tid = threadIdx.x;
  const float4* s4 = reinterpret_cast<const float4*>(src);
  u16* dt = dst + (size_t)tile * 65536;
#pragma unroll 1
  for (int it = 0; it < 32; ++it) {
    int idx = tid + it * 256;              // 0..8191
    int G = idx & 3, row = (idx >> 2) & 127, step = idx >> 9;
    int srow = tile * 128 + row;
    int kb = (step & 7) * 32 + 8 * (G ^ swz4(row));
    float4 a = s4[srow * 64 + (kb >> 2)];
    float4 b = s4[srow * 64 + (kb >> 2) + 1];
    float v[8] = {a.x, a.y, a.z, a.w, b.x, b.y, b.z, b.w};
    union { u16 us[8]; uint4 vec; } pk;
    if (step < 8) {
#pragma unroll
      for (int j = 0; j < 8; ++j) pk.us[j] = f2bf(v[j]);
    } else {
#pragma unroll
      for (int j = 0; j < 8; ++j) {
        float h1 = bf2f(f2bf(v[j]));
        pk.us[j] = f2bf(v[j] - h1);        // x-h1 exact (Sterbenz)
      }
    }
    *reinterpret_cast<uint4*>(dt + step * 4096 + row * 32 + G * 8) = pk.vec;
  }
}

// Exact cross term: sequential fmaf chain over d=0..255 -- bit-identical to the
// previously verified kernel's accumulation order.
__device__ __forceinline__ float exact_cross(const float4* __restrict__ x4,
                                             const float4* __restrict__ e4,
                                             int grow, int code) {
  const float4* xr = x4 + (size_t)grow * 64;
  const float4* er = e4 + (size_t)code * 64;
  float acc = 0.0f;
#pragma unroll 8
  for (int t = 0; t < 64; ++t) {
    float4 a = xr[t], b = er[t];
    acc = __builtin_fmaf(a.x, b.x, acc);
    acc = __builtin_fmaf(a.y, b.y, acc);
    acc = __builtin_fmaf(a.z, b.z, acc);
    acc = __builtin_fmaf(a.w, b.w, acc);
  }
  return acc;
}

// Fused: MFMA split-GEMM (K=768: h1g1+h1g2+h2g1) over 128 rows x 2048 codes,
// per-chunk argmin/2nd-best + band recording, exact rescoring of near-ties,
// gather + STE output. Block = 256 thr (2x2 waves of 64x64), grid 512.
__global__ __launch_bounds__(256, 2) void vq_mfma_kernel(
    const float* __restrict__ x, const float* __restrict__ e,
    const u16* __restrict__ Xcat, const u16* __restrict__ Ecat,
    const float* __restrict__ esq_g, float* __restrict__ out,
    float* __restrict__ outIdx) {
  __shared__ __align__(16) u16 As[3][4096];   // 3-deep staged 128x32 bf16 tiles
  __shared__ __align__(16) u16 Bs[3][4096];
  __shared__ float xsq_s[128];
  __shared__ unsigned ring[RINGCAP];
  __shared__ unsigned long long ebest[128];
  __shared__ float rmv1[2][128], rmv2[2][128];
  __shared__ int rmi1[2][128];
  __shared__ int fidx[128];
  __shared__ unsigned char flg[128];
  __shared__ unsigned ringcnt, ringovf;

  const int tid = threadIdx.x;
  const int lane = tid & 63;
  const int wid = tid >> 6;
  const int wm = wid >> 1, wn = wid & 1;
  const int rowbase = blockIdx.x * 128;

  if (tid == 0) { ringcnt = 0; ringovf = 0; }
  if (tid < 128) {
    ebest[tid] = ~0ull;
    const float* xr = x + (size_t)(rowbase + tid) * D_SZ;
    xsq_s[tid] = pairwise128_sq(xr) + pairwise128_sq(xr + 128);
  }

  const u16* Asrc = Xcat + (size_t)blockIdx.x * 65536;

  // GEMM step s (0..23): A source: s<8 -> h1, 8..15 -> h1 again, 16..23 -> h2;
  //                      B source: s<8 -> g1, 8..15 -> g2, 16..23 -> g1.
  auto stage = [&](int bufi, int s, int ch) {
    const int stA = (s < 8) ? s : (s - 8);
    const int stB = (s < 16) ? s : (s - 16);
    const u16* ga = Asrc + stA * 4096 + wid * 1024 + (lane << 3);
    const u16* gb = Ecat + (size_t)ch * 65536 + stB * 4096 + wid * 1024 + (lane << 3);
    u16* la = &As[bufi][wid * 1024];
    u16* lb = &Bs[bufi][wid * 1024];
    GLOAD_LDS16(ga, la);
    GLOAD_LDS16(ga + 512, la + 512);
    GLOAD_LDS16(gb, lb);
    GLOAD_LDS16(gb + 512, lb + 512);
  };

  f32x4 acc[4][4];
#pragma unroll
  for (int mf = 0; mf < 4; ++mf)
#pragma unroll
    for (int nf = 0; nf < 4; ++nf)
#pragma unroll
      for (int j = 0; j < 4; ++j) acc[mf][nf][j] = 0.0f;

  float v1[16], v2[16];
  int i1[16];
#pragma unroll
  for (int r = 0; r < 16; ++r) { v1[r] = 3.4e38f; v2[r] = 3.4e38f; i1[r] = 0; }

  // prologue: stage gs=0,1 (2-deep lookahead, 3 buffers)
  stage(0, 0, 0);
  stage(1, 1, 0);
  asm volatile("s_waitcnt vmcnt(4)");
  __builtin_amdgcn_s_barrier();

  int buf = 0, s = 0, chunk = 0;
  int sl = 2, chl = 0;  // lookahead (gs+2) position
#pragma unroll 1
  for (int gs = 0; gs < 384; ++gs) {
    const bool dostage = (gs + 2 < 384);
    if (dostage) {
      int b2 = buf - 1; if (b2 < 0) b2 += 3;   // (buf+2)%3
      stage(b2, sl, chl);
      if (++sl == 24) { sl = 0; ++chl; }
    }
    // fragments: A row = lane&15 (+16*mf+64*wm), k-group = (lane>>4), swizzled
    bf16x8 af[4], bfr[4];
#pragma unroll
    for (int mf = 0; mf < 4; ++mf) {
      const int rowA = wm * 64 + mf * 16 + (lane & 15);
      const int G = (lane >> 4) ^ swz4(rowA);
      af[mf] = *reinterpret_cast<const bf16x8*>(&As[buf][rowA * 32 + G * 8]);
    }
#pragma unroll
    for (int nf = 0; nf < 4; ++nf) {
      const int rowB = wn * 64 + nf * 16 + (lane & 15);
      const int G = (lane >> 4) ^ swz4(rowB);
      bfr[nf] = *reinterpret_cast<const bf16x8*>(&Bs[buf][rowB * 32 + G * 8]);
    }
#pragma unroll
    for (int mf = 0; mf < 4; ++mf)
#pragma unroll
      for (int nf = 0; nf < 4; ++nf)
        acc[mf][nf] =
            __builtin_amdgcn_mfma_f32_16x16x32_bf16(af[mf], bfr[nf], acc[mf][nf], 0, 0, 0);

    // counted vmcnt: leave next-next stage (4 issues/wave) in flight
    if (dostage) asm volatile("s_waitcnt vmcnt(4)");
    else asm volatile("s_waitcnt vmcnt(0)");
    __builtin_amdgcn_s_barrier();
    if (++buf == 3) buf = 0;

    if (++s == 24) {
      s = 0;
      // ---- chunk epilogue: dist, running top-2, band recording ----
      float esq_c[4];
#pragma unroll
      for (int nf = 0; nf < 4; ++nf)
        esq_c[nf] = esq_g[chunk * 128 + wn * 64 + nf * 16 + (lane & 15)];
#pragma unroll
      for (int mf = 0; mf < 4; ++mf) {
#pragma unroll
        for (int rg = 0; rg < 4; ++rg) {
          const int r16 = mf * 4 + rg;
          const int row = wm * 64 + mf * 16 + (lane >> 4) * 4 + rg;  // C layout (m89)
          const float xq = xsq_s[row];
          float dv[4];
          float dmin = 3.4e38f;
#pragma unroll
          for (int nf = 0; nf < 4; ++nf) {
            dv[nf] = (xq - 2.0f * acc[mf][nf][rg]) + esq_c[nf];
            dmin = fminf(dmin, dv[nf]);
          }
          // segment min over this wave's 64 cols for this row (lanes share l>>4)
          float sm = dmin;
          sm = fminf(sm, __shfl_xor(sm, 1, 64));
          sm = fminf(sm, __shfl_xor(sm, 2, 64));
          sm = fminf(sm, __shfl_xor(sm, 4, 64));
          sm = fminf(sm, __shfl_xor(sm, 8, 64));
          const float thr = sm + EPS_GAP;
#pragma unroll
          for (int nf = 0; nf < 4; ++nf) {
            const int code = chunk * 128 + wn * 64 + nf * 16 + (lane & 15);
            if (dv[nf] < v1[r16]) {
              v2[r16] = v1[r16]; v1[r16] = dv[nf]; i1[r16] = code;
            } else if (dv[nf] < v2[r16]) {
              v2[r16] = dv[nf];
            }
            if (dv[nf] <= thr) {  // band superset of any possible exact winner
              unsigned slot = atomicAdd(&ringcnt, 1u);
              if (slot < RINGCAP) ring[slot] = ((unsigned)row << 11) | (unsigned)code;
              else ringovf = 1u;
            }
          }
        }
      }
#pragma unroll
      for (int mf = 0; mf < 4; ++mf)
#pragma unroll
        for (int nf = 0; nf < 4; ++nf)
#pragma unroll
          for (int j = 0; j < 4; ++j) acc[mf][nf][j] = 0.0f;
      ++chunk;
    }
  }

  // ---- per-row merge: 16 lanes of each row-group, then the two wave-halves ----
#pragma unroll
  for (int r = 0; r < 16; ++r) {
#pragma unroll
    for (int m = 1; m < 16; m <<= 1) {
      float ov1 = __shfl_xor(v1[r], m, 64);
      int oi1 = __shfl_xor(i1[r], m, 64);
      float ov2 = __shfl_xor(v2[r], m, 64);
      bool take = (ov1 < v1[r]) || (ov1 == v1[r] && oi1 < i1[r]);
      float nv2 = take ? fminf(v1[r], ov2) : fminf(ov1, v2[r]);
      if (take) { v1[r] = ov1; i1[r] = oi1; }
      v2[r] = nv2;
    }
  }
  if ((lane & 15) == 0) {
#pragma unroll
    for (int mf = 0; mf < 4; ++mf)
#pragma unroll
      for (int rg = 0; rg < 4; ++rg) {
        const int row = wm * 64 + mf * 16 + (lane >> 4) * 4 + rg;
        const int r16 = mf * 4 + rg;
        rmv1[wn][row] = v1[r16];
        rmi1[wn][row] = i1[r16];
        rmv2[wn][row] = v2[r16];
      }
  }
  __syncthreads();
  if (tid < 128) {
    float a1 = rmv1[0][tid], b1 = rmv1[1][tid];
    int ai = rmi1[0][tid], bi = rmi1[1][tid];
    float a2 = rmv2[0][tid], b2 = rmv2[1][tid];
    bool take = (b1 < a1) || (b1 == a1 && bi < ai);
    float v1u = take ? b1 : a1;
    int i1u = take ? bi : ai;
    float v2u = take ? fminf(a1, b2) : fminf(b1, a2);
    fidx[tid] = i1u;
    flg[tid] = (v2u - v1u <= EPS_GAP) ? 1 : 0;
  }
  __syncthreads();

  // ---- exact rescoring of flagged rows over banded candidates ----
  const float4* x4 = reinterpret_cast<const float4*>(x);
  const float4* e4 = reinterpret_cast<const float4*>(e);
  const unsigned cnt = ringcnt;
  if (ringovf == 0) {
    for (unsigned i = tid; i < cnt; i += 256) {
      const unsigned ent = ring[i];
      const int row = (int)(ent >> 11), code = (int)(ent & 2047u);
      if (flg[row]) {
        const float cr = exact_cross(x4, e4, rowbase + row, code);
        const float d = (xsq_s[row] - 2.0f * cr) + esq_g[code];
        const unsigned long long key =
            (((unsigned long long)__float_as_uint(d)) << 32) | (unsigned)code;
        atomicMin(&ebest[row], key);  // min dist, tie -> lowest code (np rule)
      }
    }
  } else {  // ring overflow (statistically ~impossible): full exact scan
#pragma unroll 1
    for (int row = 0; row < 128; ++row) {
      if (flg[row]) {
        for (int code = tid; code < K_SZ; code += 256) {
          const float cr = exact_cross(x4, e4, rowbase + row, code);
          const float d = (xsq_s[row] - 2.0f * cr) + esq_g[code];
          const unsigned long long key =
              (((unsigned long long)__float_as_uint(d)) << 32) | (unsigned)code;
          atomicMin(&ebest[row], key);
        }
      }
    }
  }
  __syncthreads();
  if (tid < 128 && flg[tid]) fidx[tid] = (int)(ebest[tid] & 2047ull);
  __syncthreads();

  // ---- output: overwrites this block's own (already consumed) Xcat tile ----
  float4* out4 = reinterpret_cast<float4*>(out);
#pragma unroll 1
  for (int i = tid; i < 128 * 64; i += 256) {
    const int row = i >> 6, q = i & 63;
    const int idx = fidx[row];
    float4 xv = x4[(size_t)(rowbase + row) * 64 + q];
    float4 qv = e4[(size_t)idx * 64 + q];
    float4 o;
    o.x = xv.x + (qv.x - xv.x);
    o.y = xv.y + (qv.y - xv.y);
    o.z = xv.z + (qv.z - xv.z);
    o.w = xv.w + (qv.w - xv.w);
    out4[(size_t)(rowbase + row) * 64 + q] = o;
    if (q == 0) outIdx[rowbase + row] = (float)idx;
  }
}

extern "C" void kernel_launch(void* const* d_in, const int* in_sizes, int n_in,
                              void* d_out, int out_size, void* d_ws, size_t ws_size,
                              hipStream_t stream) {
  const float* x = (const float*)d_in[0];      // (65536, 256) fp32
  const float* e = (const float*)d_in[1];      // (2048, 256) fp32
  float* out = (float*)d_out;                  // [T*D quantized | T indices-as-float]
  float* outIdx = out + (size_t)T_SZ * D_SZ;

  float* esq = (float*)d_ws;                   // 2048 floats
  u16* Ecat = (u16*)(esq + K_SZ);              // 2 MB split-bf16 codebook image
  // Xcat (64 MB split-bf16 x image) lives in the quantized-output region:
  // block b reads only tile b and overwrites it with its own output afterwards.
  u16* Xcat = (u16*)out;

  conv_kernel<<<T_SZ / 128, 256, 0, stream>>>(x, Xcat);
  conv_kernel<<<K_SZ / 128, 256, 0, stream>>>(e, Ecat);
  esq_kernel<<<K_SZ / 64, 64, 0, stream>>>(e, esq);
  vq_mfma_kernel<<<T_SZ / 128, 256, 0, stream>>>(x, e, Xcat, Ecat, esq, out, outIdx);
}

// Round 3
// 416.967 us; speedup vs baseline: 2.8035x; 2.0352x over previous
//
#include <hip/hip_runtime.h>

#define T_SZ 65536
#define K_SZ 2048
#define D_SZ 256

typedef unsigned short u16;
typedef _Float16 f16;
typedef f16 f16x8 __attribute__((ext_vector_type(8)));
typedef float f32x4 __attribute__((ext_vector_type(4)));

// Candidate ring capacity. Expected load ~8 entries/row (~1030/block) with the
// warmed shared-running-min gate; 3072 is ~3x headroom. Overflow -> exact full
// scan fallback (correct, slow, statistically unreachable).
#define RINGCAP 3072

#define GLOAD_LDS16(g, l)                                                  \
  __builtin_amdgcn_global_load_lds(                                        \
      (const __attribute__((address_space(1))) unsigned int*)(g),          \
      (__attribute__((address_space(3))) unsigned int*)(l), 16, 0, 0)

// bank-swizzle key for 16B k-groups within a 64B row. Baked into the global
// fp16 images by conv_kernel and inverted at fragment-read time (G21:
// both-sides-or-neither), so it is correctness-neutral by construction.
__device__ __forceinline__ int swz4(int r) { return (r & 3) ^ ((r >> 2) & 3); }

// numpy pairwise_sum replica for 128 contiguous squared elements (verified).
__device__ __forceinline__ float pairwise128_sq(const float* __restrict__ a) {
#pragma clang fp contract(off)
  float r0 = a[0] * a[0], r1 = a[1] * a[1], r2 = a[2] * a[2], r3 = a[3] * a[3];
  float r4 = a[4] * a[4], r5 = a[5] * a[5], r6 = a[6] * a[6], r7 = a[7] * a[7];
#pragma unroll
  for (int i = 8; i < 128; i += 8) {
    r0 += a[i + 0] * a[i + 0];
    r1 += a[i + 1] * a[i + 1];
    r2 += a[i + 2] * a[i + 2];
    r3 += a[i + 3] * a[i + 3];
    r4 += a[i + 4] * a[i + 4];
    r5 += a[i + 5] * a[i + 5];
    r6 += a[i + 6] * a[i + 6];
    r7 += a[i + 7] * a[i + 7];
  }
  return ((r0 + r1) + (r2 + r3)) + ((r4 + r5) + (r6 + r7));
}

// Same exact pairwise xsq chain + loose |x| sum (any order; only used inside
// our own rigorous error bound, with slack in the constants).
__device__ __forceinline__ float2 pairwise128_sq_abs(const float* __restrict__ a) {
#pragma clang fp contract(off)
  float r0 = a[0] * a[0], r1 = a[1] * a[1], r2 = a[2] * a[2], r3 = a[3] * a[3];
  float r4 = a[4] * a[4], r5 = a[5] * a[5], r6 = a[6] * a[6], r7 = a[7] * a[7];
  float s0 = fabsf(a[0]) + fabsf(a[1]), s1 = fabsf(a[2]) + fabsf(a[3]);
  float s2 = fabsf(a[4]) + fabsf(a[5]), s3 = fabsf(a[6]) + fabsf(a[7]);
#pragma unroll
  for (int i = 8; i < 128; i += 8) {
    r0 += a[i + 0] * a[i + 0];
    r1 += a[i + 1] * a[i + 1];
    r2 += a[i + 2] * a[i + 2];
    r3 += a[i + 3] * a[i + 3];
    r4 += a[i + 4] * a[i + 4];
    r5 += a[i + 5] * a[i + 5];
    r6 += a[i + 6] * a[i + 6];
    r7 += a[i + 7] * a[i + 7];
    s0 += fabsf(a[i + 0]) + fabsf(a[i + 1]);
    s1 += fabsf(a[i + 2]) + fabsf(a[i + 3]);
    s2 += fabsf(a[i + 4]) + fabsf(a[i + 5]);
    s3 += fabsf(a[i + 6]) + fabsf(a[i + 7]);
  }
  float2 res;
  res.x = ((r0 + r1) + (r2 + r3)) + ((r4 + r5) + (r6 + r7));
  res.y = (s0 + s1) + (s2 + s3);
  return res;
}

__global__ void esq_kernel(const float* __restrict__ e, float* __restrict__ esq) {
  int k = blockIdx.x * 64 + threadIdx.x;
  const float* er = e + (size_t)k * D_SZ;
  esq[k] = pairwise128_sq(er) + pairwise128_sq(er + 128);
}

// fp32 rows -> pre-tiled, pre-swizzled fp16 image (RNE via v_cvt_f16_f32).
// Per 128-row tile: [kstep 0..7][row 0..127][G 0..3][j 0..7],
// element (row, k = kstep*32 + 8*(G ^ swz4(row)) + j).
__global__ __launch_bounds__(256) void conv_kernel(const float* __restrict__ src,
                                                   u16* __restrict__ dst,
                                                   int tile_stride) {
  const int tile = blockIdx.x, tid = threadIdx.x;
  const float4* s4 = reinterpret_cast<const float4*>(src);
  u16* dt = dst + (size_t)tile * tile_stride;
#pragma unroll 1
  for (int it = 0; it < 16; ++it) {
    int idx = tid + it * 256;  // 0..4095
    int G = idx & 3, row = (idx >> 2) & 127, step = idx >> 9;  // step 0..7
    int srow = tile * 128 + row;
    int kb = step * 32 + 8 * (G ^ swz4(row));
    float4 a = s4[srow * 64 + (kb >> 2)];
    float4 b = s4[srow * 64 + (kb >> 2) + 1];
    float v[8] = {a.x, a.y, a.z, a.w, b.x, b.y, b.z, b.w};
    union { f16 h[8]; uint4 vec; } pk;
#pragma unroll
    for (int j = 0; j < 8; ++j) pk.h[j] = (f16)v[j];
    *reinterpret_cast<uint4*>(dt + (size_t)step * 4096 + row * 32 + G * 8) = pk.vec;
  }
}

// Exact cross term: sequential fmaf chain over d=0..255 -- bit-identical to the
// harness-verified chain from previous rounds.
__device__ __forceinline__ float exact_cross(const float4* __restrict__ x4,
                                             const float4* __restrict__ e4,
                                             int grow, int code) {
  const float4* xr = x4 + (size_t)grow * 64;
  const float4* er = e4 + (size_t)code * 64;
  float acc = 0.0f;
#pragma unroll 8
  for (int t = 0; t < 64; ++t) {
    float4 a = xr[t], b = er[t];
    acc = __builtin_fmaf(a.x, b.x, acc);
    acc = __builtin_fmaf(a.y, b.y, acc);
    acc = __builtin_fmaf(a.z, b.z, acc);
    acc = __builtin_fmaf(a.w, b.w, acc);
  }
  return acc;
}

// Fused: fp16 MFMA GEMM (K=256, A in registers, B streamed 3-deep through LDS),
// shared-running-min gated candidate ring, exact rescoring of all ring entries,
// gather + STE output. Block = 256 thr (2x2 waves of 64x64), grid 512.
__global__ __launch_bounds__(256, 2) void vq_mfma_kernel(
    const float* __restrict__ x, const float* __restrict__ e,
    const u16* __restrict__ Xh, const u16* __restrict__ Eh,
    const float* __restrict__ esq_g, float* __restrict__ out,
    float* __restrict__ outIdx) {
  __shared__ __align__(16) u16 Bs[3][8192];  // 3 x 16KB (BK=64 B tiles)
  __shared__ float xsq_s[128], th_s[128];
  __shared__ unsigned rm1_u[128];            // running min dist (uint-ordered)
  __shared__ unsigned ring[RINGCAP];
  __shared__ unsigned long long ebest[128];
  __shared__ int fidx[128];
  __shared__ unsigned ringcnt;

  const int tid = threadIdx.x;
  const int lane = tid & 63;
  const int wid = tid >> 6;
  const int wm = wid >> 1, wn = wid & 1;
  const int rowbase = blockIdx.x * 128;

  if (tid == 0) ringcnt = 0;
  if (tid < 128) {
    ebest[tid] = ~0ull;
    rm1_u[tid] = 0x7F7FFFFFu;  // +FLT_MAX
    const float* xr = x + (size_t)(rowbase + tid) * D_SZ;
    float2 p0 = pairwise128_sq_abs(xr);
    float2 p1 = pairwise128_sq_abs(xr + 128);
    xsq_s[tid] = p0.x + p1.x;
    // Rigorous per-row band threshold (>=2x margin over the derived
    // |approx-exact| dist bound: 1.94e-6*Sa + 1.24e-4).
    th_s[tid] = 4.0e-6f * (p0.y + p1.y) + 4.0e-4f;
  }

  // A fragments (this wave's 64 rows x 256 k) -> 128 VGPR. Each (mf,ks) read is
  // a perfect permutation of a contiguous 1KB block: fully coalesced.
  const u16* At = Xh + (size_t)blockIdx.x * 65536;
  f16x8 af[4][8];
#pragma unroll
  for (int mf = 0; mf < 4; ++mf) {
    const int rowA = wm * 64 + mf * 16 + (lane & 15);
    const int offA = rowA * 32 + (((lane >> 4) ^ swz4(rowA)) * 8);
#pragma unroll
    for (int ks = 0; ks < 8; ++ks)
      af[mf][ks] = *reinterpret_cast<const f16x8*>(At + ks * 4096 + offA);
  }

  // B fragment LDS offsets (u16 units), constant per thread.
  int offB[4];
#pragma unroll
  for (int nf = 0; nf < 4; ++nf) {
    const int cl = wn * 64 + nf * 16 + (lane & 15);
    offB[nf] = cl * 32 + (((lane >> 4) ^ swz4(cl)) * 8);
  }

  f32x4 acc[4][4];
#pragma unroll
  for (int mf = 0; mf < 4; ++mf)
#pragma unroll
    for (int nf = 0; nf < 4; ++nf) acc[mf][nf] = (f32x4){0.f, 0.f, 0.f, 0.f};

  // Compute-step position p in [0,68): p<4 = pre-pass over chunk 0 (warms rm1,
  // no recording); p>=4 = main chunks 0..15 with recording.
  auto stage = [&](int bufi, int p) {
    const int chk = (p < 4) ? 0 : ((p - 4) >> 2);
    const int st = (p < 4) ? p : ((p - 4) & 3);
    const u16* g = Eh + chk * 32768 + st * 8192 + wid * 2048 + lane * 8;
    u16* l = &Bs[bufi][wid * 2048];
    GLOAD_LDS16(g, l);
    GLOAD_LDS16(g + 512, l + 512);
    GLOAD_LDS16(g + 1024, l + 1024);
    GLOAD_LDS16(g + 1536, l + 1536);
  };

  stage(0, 0);
  stage(1, 1);
  asm volatile("s_waitcnt vmcnt(4)");
  __syncthreads();

  int bufc = 0;
  const volatile unsigned* rmv = rm1_u;

#pragma unroll 1
  for (int ch = -1; ch < 16; ++ch) {
    const int chunk = (ch < 0) ? 0 : ch;
    float esq_c[4];
#pragma unroll
    for (int nf = 0; nf < 4; ++nf)
      esq_c[nf] = esq_g[chunk * 128 + wn * 64 + nf * 16 + (lane & 15)];
#pragma unroll
    for (int s = 0; s < 4; ++s) {
      const int t = (ch + 1) * 4 + s;
      const bool dostage = (t + 2 < 68);
      if (dostage) {
        int b2 = bufc + 2;
        if (b2 >= 3) b2 -= 3;
        stage(b2, t + 2);
      }
      const u16* bb = &Bs[bufc][0];
#pragma unroll
      for (int kk = 0; kk < 2; ++kk) {
        f16x8 bfr[4];
#pragma unroll
        for (int nf = 0; nf < 4; ++nf)
          bfr[nf] = *reinterpret_cast<const f16x8*>(bb + kk * 4096 + offB[nf]);
#pragma unroll
        for (int mf = 0; mf < 4; ++mf)
#pragma unroll
          for (int nf = 0; nf < 4; ++nf)
            acc[mf][nf] = __builtin_amdgcn_mfma_f32_16x16x32_f16(
                af[mf][s * 2 + kk], bfr[nf], acc[mf][nf], 0, 0, 0);
      }
      if (dostage) asm volatile("s_waitcnt vmcnt(4)");
      else asm volatile("s_waitcnt vmcnt(0)");
      __builtin_amdgcn_s_barrier();
      if (++bufc == 3) bufc = 0;
    }
    // ---- chunk epilogue: dist, ring recording (gated), rm1 update ----
    const bool record = (ch >= 0);
    const int cbase = chunk * 128 + wn * 64;
#pragma unroll
    for (int mf = 0; mf < 4; ++mf) {
#pragma unroll
      for (int rg = 0; rg < 4; ++rg) {
        const int row = wm * 64 + mf * 16 + (lane >> 4) * 4 + rg;  // C layout (m89)
        const float xq = xsq_s[row];
        const float rm = __uint_as_float(rmv[row]);  // stale-tolerant (monotone)
        float dv[4];
#pragma unroll
        for (int nf = 0; nf < 4; ++nf)
          dv[nf] = (xq - 2.0f * acc[mf][nf][rg]) + esq_c[nf];
        const float dmin = fminf(fminf(dv[0], dv[1]), fminf(dv[2], dv[3]));
        if (record) {
          const float gate = rm + th_s[row];  // rm >= final global min -> sound
#pragma unroll
          for (int nf = 0; nf < 4; ++nf) {
            if (dv[nf] < gate) {
              unsigned slot = atomicAdd(&ringcnt, 1u);
              if (slot < RINGCAP)
                ring[slot] = ((unsigned)row << 11) |
                             (unsigned)(cbase + nf * 16 + (lane & 15));
            }
          }
        }
        if (dmin < rm) atomicMin(&rm1_u[row], __float_as_uint(dmin));
      }
    }
#pragma unroll
    for (int mf = 0; mf < 4; ++mf)
#pragma unroll
      for (int nf = 0; nf < 4; ++nf) acc[mf][nf] = (f32x4){0.f, 0.f, 0.f, 0.f};
  }
  __syncthreads();

  // ---- exact rescoring of every ring entry (winner + all ties provably in) --
  const float4* x4 = reinterpret_cast<const float4*>(x);
  const float4* e4 = reinterpret_cast<const float4*>(e);
  const unsigned cnt = ringcnt;
  if (cnt <= RINGCAP) {
    for (unsigned i = tid; i < cnt; i += 256) {
      const unsigned ent = ring[i];
      const int row = (int)(ent >> 11), code = (int)(ent & 2047u);
      const float cr = exact_cross(x4, e4, rowbase + row, code);
      const float d = (xsq_s[row] - 2.0f * cr) + esq_g[code];
      const unsigned long long key =
          (((unsigned long long)__float_as_uint(d)) << 32) | (unsigned)code;
      atomicMin(&ebest[row], key);  // min dist, tie -> lowest code (np rule)
    }
  } else {  // overflow (statistically unreachable): full exact scan
#pragma unroll 1
    for (int row = 0; row < 128; ++row) {
      for (int code = tid; code < K_SZ; code += 256) {
        const float cr = exact_cross(x4, e4, rowbase + row, code);
        const float d = (xsq_s[row] - 2.0f * cr) + esq_g[code];
        const unsigned long long key =
            (((unsigned long long)__float_as_uint(d)) << 32) | (unsigned)code;
        atomicMin(&ebest[row], key);
      }
    }
  }
  __syncthreads();
  if (tid < 128) fidx[tid] = (int)(ebest[tid] & 2047ull);
  __syncthreads();

  // ---- output: overwrites this block's own (already consumed) Xh tile ----
  float4* out4 = reinterpret_cast<float4*>(out);
#pragma unroll 1
  for (int i = tid; i < 128 * 64; i += 256) {
    const int row = i >> 6, q = i & 63;
    const int idx = fidx[row];
    float4 xv = x4[(size_t)(rowbase + row) * 64 + q];
    float4 qv = e4[(size_t)idx * 64 + q];
    float4 o;
    o.x = xv.x + (qv.x - xv.x);
    o.y = xv.y + (qv.y - xv.y);
    o.z = xv.z + (qv.z - xv.z);
    o.w = xv.w + (qv.w - xv.w);
    out4[(size_t)(rowbase + row) * 64 + q] = o;
    if (q == 0) outIdx[rowbase + row] = (float)idx;
  }
}

extern "C" void kernel_launch(void* const* d_in, const int* in_sizes, int n_in,
                              void* d_out, int out_size, void* d_ws, size_t ws_size,
                              hipStream_t stream) {
  const float* x = (const float*)d_in[0];  // (65536, 256) fp32
  const float* e = (const float*)d_in[1];  // (2048, 256) fp32
  float* out = (float*)d_out;              // [T*D quantized | T indices-as-float]
  float* outIdx = out + (size_t)T_SZ * D_SZ;

  float* esq = (float*)d_ws;       // 2048 floats
  u16* Eh = (u16*)(esq + K_SZ);    // 1 MB fp16 codebook image
  // Xh (32 MB fp16 x image) lives in the quantized-output region, padded to a
  // 128KB stride so tile b sits exactly inside block b's own output rows:
  // block b reads only tile b (prologue) and overwrites that region at the end.
  u16* Xh = (u16*)out;

  conv_kernel<<<T_SZ / 128, 256, 0, stream>>>(x, Xh, 65536);
  conv_kernel<<<K_SZ / 128, 256, 0, stream>>>(e, Eh, 32768);
  esq_kernel<<<K_SZ / 64, 64, 0, stream>>>(e, esq);
  vq_mfma_kernel<<<T_SZ / 128, 256, 0, stream>>>(x, e, Xh, Eh, esq, out, outIdx);
}

// Round 4
// 405.620 us; speedup vs baseline: 2.8820x; 1.0280x over previous
//
#include <hip/hip_runtime.h>

#define T_SZ 65536
#define K_SZ 2048
#define D_SZ 256

typedef unsigned short u16;
typedef _Float16 f16;
typedef f16 f16x8 __attribute__((ext_vector_type(8)));
typedef float f32x4 __attribute__((ext_vector_type(4)));

// Candidate ring capacity. With the post-chunk-min gate the expected load is
// ~winners + near-ties ~= 150/block; 2048 is >10x headroom. Overflow -> exact
// full scan fallback (correct, slow, statistically unreachable).
#define RINGCAP 2048

#define GLOAD_LDS16(g, l)                                                  \
  __builtin_amdgcn_global_load_lds(                                        \
      (const __attribute__((address_space(1))) unsigned int*)(g),          \
      (__attribute__((address_space(3))) unsigned int*)(l), 16, 0, 0)

// bank-swizzle key for 16B k-groups within a 64B row. Baked into the global
// fp16 E image by conv_kernel and inverted at fragment-read time (G21:
// both-sides-or-neither), so it is correctness-neutral by construction.
__device__ __forceinline__ int swz4(int r) { return (r & 3) ^ ((r >> 2) & 3); }

// numpy pairwise_sum replica for 128 contiguous squared elements, float4
// loads (identical FP op sequence to the verified scalar version; only the
// load width changes -- fixes the 64-rows-per-instruction TA probe storm).
__device__ __forceinline__ float pairwise128_sq_v4(const float4* __restrict__ a4) {
#pragma clang fp contract(off)
  float4 va = a4[0], vb = a4[1];
  float r0 = va.x * va.x, r1 = va.y * va.y, r2 = va.z * va.z, r3 = va.w * va.w;
  float r4 = vb.x * vb.x, r5 = vb.y * vb.y, r6 = vb.z * vb.z, r7 = vb.w * vb.w;
#pragma unroll
  for (int i = 2; i < 32; i += 2) {
    float4 c = a4[i], d = a4[i + 1];
    r0 += c.x * c.x;
    r1 += c.y * c.y;
    r2 += c.z * c.z;
    r3 += c.w * c.w;
    r4 += d.x * d.x;
    r5 += d.y * d.y;
    r6 += d.z * d.z;
    r7 += d.w * d.w;
  }
  return ((r0 + r1) + (r2 + r3)) + ((r4 + r5) + (r6 + r7));
}

// Same exact chain + loose |x| sum (only feeds our own rigorous error bound).
__device__ __forceinline__ float2 pairwise128_sq_abs_v4(const float4* __restrict__ a4) {
#pragma clang fp contract(off)
  float4 va = a4[0], vb = a4[1];
  float r0 = va.x * va.x, r1 = va.y * va.y, r2 = va.z * va.z, r3 = va.w * va.w;
  float r4 = vb.x * vb.x, r5 = vb.y * vb.y, r6 = vb.z * vb.z, r7 = vb.w * vb.w;
  float s0 = fabsf(va.x) + fabsf(va.y), s1 = fabsf(va.z) + fabsf(va.w);
  float s2 = fabsf(vb.x) + fabsf(vb.y), s3 = fabsf(vb.z) + fabsf(vb.w);
#pragma unroll
  for (int i = 2; i < 32; i += 2) {
    float4 c = a4[i], d = a4[i + 1];
    r0 += c.x * c.x;
    r1 += c.y * c.y;
    r2 += c.z * c.z;
    r3 += c.w * c.w;
    r4 += d.x * d.x;
    r5 += d.y * d.y;
    r6 += d.z * d.z;
    r7 += d.w * d.w;
    s0 += fabsf(c.x) + fabsf(c.y);
    s1 += fabsf(c.z) + fabsf(c.w);
    s2 += fabsf(d.x) + fabsf(d.y);
    s3 += fabsf(d.z) + fabsf(d.w);
  }
  float2 res;
  res.x = ((r0 + r1) + (r2 + r3)) + ((r4 + r5) + (r6 + r7));
  res.y = (s0 + s1) + (s2 + s3);
  return res;
}

__global__ void esq_kernel(const float* __restrict__ e, float* __restrict__ esq) {
  int k = blockIdx.x * 64 + threadIdx.x;
  const float4* er = reinterpret_cast<const float4*>(e + (size_t)k * D_SZ);
  esq[k] = pairwise128_sq_v4(er) + pairwise128_sq_v4(er + 32);
}

// fp32 rows -> pre-tiled, pre-swizzled fp16 image (RNE via v_cvt_f16_f32).
// Per 128-row tile: [kstep 0..7][row 0..127][G 0..3][j 0..7],
// element (row, k = kstep*32 + 8*(G ^ swz4(row)) + j). E only (A is converted
// in-register by the main kernel).
__global__ __launch_bounds__(256) void conv_kernel(const float* __restrict__ src,
                                                   u16* __restrict__ dst) {
  const int tile = blockIdx.x, tid = threadIdx.x;
  const float4* s4 = reinterpret_cast<const float4*>(src);
  u16* dt = dst + (size_t)tile * 32768;
#pragma unroll 1
  for (int it = 0; it < 16; ++it) {
    int idx = tid + it * 256;  // 0..4095
    int G = idx & 3, row = (idx >> 2) & 127, step = idx >> 9;  // step 0..7
    int srow = tile * 128 + row;
    int kb = step * 32 + 8 * (G ^ swz4(row));
    float4 a = s4[srow * 64 + (kb >> 2)];
    float4 b = s4[srow * 64 + (kb >> 2) + 1];
    float v[8] = {a.x, a.y, a.z, a.w, b.x, b.y, b.z, b.w};
    union { f16 h[8]; uint4 vec; } pk;
#pragma unroll
    for (int j = 0; j < 8; ++j) pk.h[j] = (f16)v[j];
    *reinterpret_cast<uint4*>(dt + (size_t)step * 4096 + row * 32 + G * 8) = pk.vec;
  }
}

// Exact cross term: sequential fmaf chain over d=0..255 -- bit-identical to the
// harness-verified chain from previous rounds.
__device__ __forceinline__ float exact_cross(const float4* __restrict__ x4,
                                             const float4* __restrict__ e4,
                                             int grow, int code) {
  const float4* xr = x4 + (size_t)grow * 64;
  const float4* er = e4 + (size_t)code * 64;
  float acc = 0.0f;
#pragma unroll 8
  for (int t = 0; t < 64; ++t) {
    float4 a = xr[t], b = er[t];
    acc = __builtin_fmaf(a.x, b.x, acc);
    acc = __builtin_fmaf(a.y, b.y, acc);
    acc = __builtin_fmaf(a.z, b.z, acc);
    acc = __builtin_fmaf(a.w, b.w, acc);
  }
  return acc;
}

// Fused: fp16 MFMA GEMM (K=256, A converted fp32->fp16 in-register at the
// prologue, B streamed 3-deep through LDS), post-chunk-min gated candidate
// ring, exact rescoring of all ring entries, gather + STE output.
// Block = 256 thr (2x2 waves of 64x64), grid 512.
__global__ __launch_bounds__(256, 2) void vq_mfma_kernel(
    const float* __restrict__ x, const float* __restrict__ e,
    const u16* __restrict__ Eh, const float* __restrict__ esq_g,
    float* __restrict__ out, float* __restrict__ outIdx) {
  __shared__ __align__(16) u16 Bs[3][8192];  // 3 x 16KB (BK=64 B tiles)
  __shared__ float xsq_s[128], th_s[128];
  __shared__ unsigned rm1_u[128];            // running min dist (uint-ordered)
  __shared__ unsigned ring[RINGCAP];
  __shared__ unsigned long long ebest[128];
  __shared__ int fidx[128];
  __shared__ unsigned ringcnt;

  const int tid = threadIdx.x;
  const int lane = tid & 63;
  const int wid = tid >> 6;
  const int wm = wid >> 1, wn = wid & 1;
  const int rowbase = blockIdx.x * 128;

  if (tid == 0) ringcnt = 0;
  if (tid < 128) {
    ebest[tid] = ~0ull;
    rm1_u[tid] = 0x7F7FFFFFu;  // +FLT_MAX
  }

  auto stage = [&](int bufi, int gs) {
    const u16* g = Eh + (gs >> 2) * 32768 + (gs & 3) * 8192 + wid * 2048 + lane * 8;
    u16* l = &Bs[bufi][wid * 2048];
    GLOAD_LDS16(g, l);
    GLOAD_LDS16(g + 512, l + 512);
    GLOAD_LDS16(g + 1024, l + 1024);
    GLOAD_LDS16(g + 1536, l + 1536);
  };
  // start the B pipeline before any prologue compute
  stage(0, 0);
  stage(1, 1);

  const float4* x4 = reinterpret_cast<const float4*>(x);

  // A fragments converted directly from fp32 x (identical RNE cvt as the old
  // image path; fragment needs k = ks*32 + (lane>>4)*8 + j, which is 8
  // contiguous floats = 2 float4 loads within a 16-row/128B-coalesced group).
  f16x8 af[4][8];
#pragma unroll
  for (int mf = 0; mf < 4; ++mf) {
    const int rowA = rowbase + wm * 64 + mf * 16 + (lane & 15);
    const size_t base = (size_t)rowA * 64 + (lane >> 4) * 2;
#pragma unroll
    for (int ks = 0; ks < 8; ++ks) {
      float4 a = x4[base + ks * 8];
      float4 b = x4[base + ks * 8 + 1];
      f16x8 t;
      t[0] = (f16)a.x; t[1] = (f16)a.y; t[2] = (f16)a.z; t[3] = (f16)a.w;
      t[4] = (f16)b.x; t[5] = (f16)b.y; t[6] = (f16)b.z; t[7] = (f16)b.w;
      af[mf][ks] = t;
    }
  }

  if (tid < 128) {
    const float4* xr = x4 + (size_t)(rowbase + tid) * 64;
    float2 p0 = pairwise128_sq_abs_v4(xr);
    float2 p1 = pairwise128_sq_abs_v4(xr + 32);
    xsq_s[tid] = p0.x + p1.x;
    // Rigorous per-row band threshold (>=2x margin over the derived
    // |approx-exact| dist bound: 1.94e-6*Sa + 1.24e-4).
    th_s[tid] = 4.0e-6f * (p0.y + p1.y) + 4.0e-4f;
  }

  // B fragment LDS offsets (u16 units), constant per thread.
  int offB[4];
#pragma unroll
  for (int nf = 0; nf < 4; ++nf) {
    const int cl = wn * 64 + nf * 16 + (lane & 15);
    offB[nf] = cl * 32 + (((lane >> 4) ^ swz4(cl)) * 8);
  }

  f32x4 acc[4][4];
#pragma unroll
  for (int mf = 0; mf < 4; ++mf)
#pragma unroll
    for (int nf = 0; nf < 4; ++nf) acc[mf][nf] = (f32x4){0.f, 0.f, 0.f, 0.f};

  asm volatile("s_waitcnt vmcnt(0)");
  __syncthreads();

  int bufc = 0;
#pragma unroll 1
  for (int chunk = 0; chunk < 16; ++chunk) {
    // esq loads issued early; consumed 4 GEMM steps later (latency hidden,
    // and older than subsequent stage loads so no pipeline drain).
    float esq_c[4];
#pragma unroll
    for (int nf = 0; nf < 4; ++nf)
      esq_c[nf] = esq_g[chunk * 128 + wn * 64 + nf * 16 + (lane & 15)];
#pragma unroll
    for (int s = 0; s < 4; ++s) {
      const int gs = chunk * 4 + s;
      const bool dostage = (gs + 2 < 64);
      if (dostage) {
        int b2 = bufc + 2;
        if (b2 >= 3) b2 -= 3;
        stage(b2, gs + 2);
      }
      const u16* bb = &Bs[bufc][0];
#pragma unroll
      for (int kk = 0; kk < 2; ++kk) {
        f16x8 bfr[4];
#pragma unroll
        for (int nf = 0; nf < 4; ++nf)
          bfr[nf] = *reinterpret_cast<const f16x8*>(bb + kk * 4096 + offB[nf]);
#pragma unroll
        for (int mf = 0; mf < 4; ++mf)
#pragma unroll
          for (int nf = 0; nf < 4; ++nf)
            acc[mf][nf] = __builtin_amdgcn_mfma_f32_16x16x32_f16(
                af[mf][s * 2 + kk], bfr[nf], acc[mf][nf], 0, 0, 0);
      }
      if (dostage) asm volatile("s_waitcnt vmcnt(4)");
      else asm volatile("s_waitcnt vmcnt(0)");
      __builtin_amdgcn_s_barrier();
      if (++bufc == 3) bufc = 0;
    }
    // ---- pass 1: per-row chunk min -> rm1 (shuffle-reduced, 1 atomic/row) --
#pragma unroll
    for (int mf = 0; mf < 4; ++mf) {
#pragma unroll
      for (int rg = 0; rg < 4; ++rg) {
        const int row = wm * 64 + mf * 16 + (lane >> 4) * 4 + rg;  // C layout (m89)
        const float xq = xsq_s[row];
        float dmin = 3.4e38f;
#pragma unroll
        for (int nf = 0; nf < 4; ++nf)
          dmin = fminf(dmin, (xq - 2.0f * acc[mf][nf][rg]) + esq_c[nf]);
        dmin = fminf(dmin, __shfl_xor(dmin, 1, 64));
        dmin = fminf(dmin, __shfl_xor(dmin, 2, 64));
        dmin = fminf(dmin, __shfl_xor(dmin, 4, 64));
        dmin = fminf(dmin, __shfl_xor(dmin, 8, 64));
        if ((lane & 15) == 0) atomicMin(&rm1_u[row], __float_as_uint(dmin));
      }
    }
    __syncthreads();
    // ---- pass 2: record with POST-chunk min gate (sound: rm >= final min
    // always, th >= 2*err -> true winner and all possible ties recorded) ----
    const int cbase = chunk * 128 + wn * 64;
#pragma unroll
    for (int mf = 0; mf < 4; ++mf) {
#pragma unroll
      for (int rg = 0; rg < 4; ++rg) {
        const int row = wm * 64 + mf * 16 + (lane >> 4) * 4 + rg;
        const float xq = xsq_s[row];
        const float gate = __uint_as_float(rm1_u[row]) + th_s[row];
#pragma unroll
        for (int nf = 0; nf < 4; ++nf) {
          const float dv = (xq - 2.0f * acc[mf][nf][rg]) + esq_c[nf];
          if (dv <= gate) {
            unsigned slot = atomicAdd(&ringcnt, 1u);
            if (slot < RINGCAP)
              ring[slot] = ((unsigned)row << 11) |
                           (unsigned)(cbase + nf * 16 + (lane & 15));
          }
        }
      }
    }
#pragma unroll
    for (int mf = 0; mf < 4; ++mf)
#pragma unroll
      for (int nf = 0; nf < 4; ++nf) acc[mf][nf] = (f32x4){0.f, 0.f, 0.f, 0.f};
  }
  __syncthreads();

  // ---- exact rescoring of every ring entry (winner + all ties provably in) --
  const float4* e4 = reinterpret_cast<const float4*>(e);
  const unsigned cnt = ringcnt;
  if (cnt <= RINGCAP) {
    for (unsigned i = tid; i < cnt; i += 256) {
      const unsigned ent = ring[i];
      const int row = (int)(ent >> 11), code = (int)(ent & 2047u);
      const float cr = exact_cross(x4, e4, rowbase + row, code);
      const float d = (xsq_s[row] - 2.0f * cr) + esq_g[code];
      const unsigned long long key =
          (((unsigned long long)__float_as_uint(d)) << 32) | (unsigned)code;
      atomicMin(&ebest[row], key);  // min dist, tie -> lowest code (np rule)
    }
  } else {  // overflow (statistically unreachable): full exact scan
#pragma unroll 1
    for (int row = 0; row < 128; ++row) {
      for (int code = tid; code < K_SZ; code += 256) {
        const float cr = exact_cross(x4, e4, rowbase + row, code);
        const float d = (xsq_s[row] - 2.0f * cr) + esq_g[code];
        const unsigned long long key =
            (((unsigned long long)__float_as_uint(d)) << 32) | (unsigned)code;
        atomicMin(&ebest[row], key);
      }
    }
  }
  __syncthreads();
  if (tid < 128) fidx[tid] = (int)(ebest[tid] & 2047ull);
  __syncthreads();

  // ---- output: gather + STE, fully coalesced ----
  float4* out4 = reinterpret_cast<float4*>(out);
#pragma unroll 1
  for (int i = tid; i < 128 * 64; i += 256) {
    const int row = i >> 6, q = i & 63;
    const int idx = fidx[row];
    float4 xv = x4[(size_t)(rowbase + row) * 64 + q];
    float4 qv = e4[(size_t)idx * 64 + q];
    float4 o;
    o.x = xv.x + (qv.x - xv.x);
    o.y = xv.y + (qv.y - xv.y);
    o.z = xv.z + (qv.z - xv.z);
    o.w = xv.w + (qv.w - xv.w);
    out4[(size_t)(rowbase + row) * 64 + q] = o;
    if (q == 0) outIdx[rowbase + row] = (float)idx;
  }
}

extern "C" void kernel_launch(void* const* d_in, const int* in_sizes, int n_in,
                              void* d_out, int out_size, void* d_ws, size_t ws_size,
                              hipStream_t stream) {
  const float* x = (const float*)d_in[0];  // (65536, 256) fp32
  const float* e = (const float*)d_in[1];  // (2048, 256) fp32
  float* out = (float*)d_out;              // [T*D quantized | T indices-as-float]
  float* outIdx = out + (size_t)T_SZ * D_SZ;

  float* esq = (float*)d_ws;     // 2048 floats
  u16* Eh = (u16*)(esq + K_SZ);  // 1 MB fp16 codebook image

  conv_kernel<<<K_SZ / 128, 256, 0, stream>>>(e, Eh);
  esq_kernel<<<K_SZ / 64, 64, 0, stream>>>(e, esq);
  vq_mfma_kernel<<<T_SZ / 128, 256, 0, stream>>>(x, e, Eh, esq, out, outIdx);
}